// Round 16
// baseline (293.840 us; speedup 1.0000x reference)
//
#include <hip/hip_runtime.h>

#define NN 50000
#define IN_DIM 128
#define HD 96
#define BN_EPS 1e-5f
#define PN_SCALE 20.0f
#define SCAN_NB 196   // ceil(50000/256)
#define NREP 4        // hist replicas (hist only; fill uses a single cursor)

using bf16x8 = __attribute__((ext_vector_type(8))) short;
using f32x4  = __attribute__((ext_vector_type(4))) float;

__device__ __forceinline__ float4 ld4(const float* p) { return *(const float4*)p; }
__device__ __forceinline__ float4 add4(float4 a, float4 b) {
    return make_float4(a.x + b.x, a.y + b.y, a.z + b.z, a.w + b.w);
}

// fp32 -> bf16 round-to-nearest-even (bit trick; no builtin dependency)
__device__ __forceinline__ short bfr(float f) {
    unsigned u = __float_as_uint(f);
    unsigned r = u + 0x7fffu + ((u >> 16) & 1u);
    return (short)(r >> 16);
}
__device__ __forceinline__ bf16x8 cvt8(float4 a, float4 b) {
    bf16x8 r;
    r[0] = bfr(a.x); r[1] = bfr(a.y); r[2] = bfr(a.z); r[3] = bfr(a.w);
    r[4] = bfr(b.x); r[5] = bfr(b.y); r[6] = bfr(b.z); r[7] = bfr(b.w);
    return r;
}

// ---------------- zero stats + replicated CSR counters ----------------
__global__ void zero_kernel(float* stats, int* cnt) {
    int i = blockIdx.x * blockDim.x + threadIdx.x;
    if (i < 1024) stats[i] = 0.0f;
    int j = i - 1024;
    if (j >= 0 && j < NREP * NN) cnt[j] = 0;
}

// ---------------- MFMA GEMM: C[N,96] = act(A[N,K]) @ W[96,K]^T + b ----------
// Round-15 A/B: replicated hist helped gemm0 (off top-5); replicated CURSORS
// hurt fill (46.5->52) -> this round: hist stays replicated, fill reverts to
// single cursor. New: C stored via LDS bounce (Cl[64][100]) -> 6 coalesced
// float4 stores/wave instead of 24 scalar dwords -> tests whether the gemms'
// WRITE_SIZE 43.6MB (vs 19.2MB output) is real store amplification or
// eviction-attribution bleed. MFMA core unchanged from passing round-14/15.
template<int K, int MODE>
__global__ __launch_bounds__(256) void gemm_mfma(
    const float* A, const float* __restrict__ W, const float* __restrict__ bias,
    float* out, const float* __restrict__ scale, const float* __restrict__ shift,
    float* __restrict__ gsum, float* __restrict__ gsumsq,
    float* __restrict__ gcol, float* __restrict__ growss,
    const int* __restrict__ ei, int* __restrict__ hist_cnt, int E)
{
    constexpr int P     = K + 8;   // bf16 pitch: 16B-aligned rows, spread banks
    constexpr int NS    = K / 32;  // K-steps
    constexpr int KD4   = K / 4;   // dword4 chunks per W row
    constexpr int WITER = (96 * KD4) / 256;   // 12 (K=128) / 9 (K=96)
    constexpr int WL_SH  = 96 * P;            // shorts actually used
    constexpr int WL_TOT = (20608 > WL_SH) ? 20608 : WL_SH;  // 41216 B
    __shared__ short Wl[WL_TOT];   // LDS caps occupancy at 3 blocks/CU (= grid)

    const int t    = threadIdx.x;
    const int l    = t & 63;
    const int w    = t >> 6;       // wave 0..3
    const int l15  = l & 15;
    const int lh   = l >> 4;       // 0..3
    const int base = blockIdx.x * 64;

    const int  arow = base + w * 16 + l15;
    const bool aok  = arow < NN;
    const float* Ap = A + (size_t)arow * K + lh * 8;
    const float4 Z4 = make_float4(0.f, 0.f, 0.f, 0.f);

    // ---- cluster ALL global loads up front ----
    float4 pa[2 * NS];
#pragma unroll
    for (int s = 0; s < NS; ++s) {
        pa[2 * s]     = aok ? ld4(Ap + s * 32)     : Z4;
        pa[2 * s + 1] = aok ? ld4(Ap + s * 32 + 4) : Z4;
    }
    float4 wv[WITER];
#pragma unroll
    for (int i = 0; i < WITER; ++i) {
        int c = t + i * 256;
        int row = c / KD4, kq = c - row * KD4;
        wv[i] = ld4(W + (size_t)row * K + kq * 4);
    }
    float4 scv[2 * NS], shv[2 * NS];
    if (MODE == 2) {
#pragma unroll
        for (int s = 0; s < 2 * NS; ++s) {
            scv[s] = ld4(scale + (s >> 1) * 32 + lh * 8 + (s & 1) * 4);
            shv[s] = ld4(shift + (s >> 1) * 32 + lh * 8 + (s & 1) * 4);
        }
    }

    if (MODE == 0) {               // fused histogram: 4 edges/thread, replicated
        int e0 = (blockIdx.x * 256 + t) * 4;   // e0 % 4 == 0 -> replica = i
        if (e0 + 4 <= E) {
            int4 d4 = *(const int4*)(ei + E + e0);
            atomicAdd(&hist_cnt[0 * NN + d4.x], 1);
            atomicAdd(&hist_cnt[1 * NN + d4.y], 1);
            atomicAdd(&hist_cnt[2 * NN + d4.z], 1);
            atomicAdd(&hist_cnt[3 * NN + d4.w], 1);
        } else {
            for (int i = 0; i < 4; ++i) {
                int e = e0 + i;
                if (e < E) atomicAdd(&hist_cnt[(e & 3) * NN + ei[E + e]], 1);
            }
        }
    }

    // ---- convert A early (waits only on A loads; frees 2*NS float4s) ----
    bf16x8 af[NS];
#pragma unroll
    for (int s = 0; s < NS; ++s) {
        float4 q0 = pa[2 * s], q1 = pa[2 * s + 1];
        if (MODE == 2) {
            float4 sc0 = scv[2 * s], sh0 = shv[2 * s];
            float4 sc1 = scv[2 * s + 1], sh1 = shv[2 * s + 1];
            q0.x = fmaxf(q0.x * sc0.x + sh0.x, 0.f);
            q0.y = fmaxf(q0.y * sc0.y + sh0.y, 0.f);
            q0.z = fmaxf(q0.z * sc0.z + sh0.z, 0.f);
            q0.w = fmaxf(q0.w * sc0.w + sh0.w, 0.f);
            q1.x = fmaxf(q1.x * sc1.x + sh1.x, 0.f);
            q1.y = fmaxf(q1.y * sc1.y + sh1.y, 0.f);
            q1.z = fmaxf(q1.z * sc1.z + sh1.z, 0.f);
            q1.w = fmaxf(q1.w * sc1.w + sh1.w, 0.f);
        }
        af[s] = cvt8(q0, q1);
    }

    // ---- convert + stage W -> bf16 LDS ----
#pragma unroll
    for (int i = 0; i < WITER; ++i) {
        int c = t + i * 256;
        int row = c / KD4, kq = c - row * KD4;
        short4 s4v;
        s4v.x = bfr(wv[i].x); s4v.y = bfr(wv[i].y);
        s4v.z = bfr(wv[i].z); s4v.w = bfr(wv[i].w);
        *(short4*)(Wl + row * P + kq * 4) = s4v;
    }
    __syncthreads();

    f32x4 acc[6];
#pragma unroll
    for (int n = 0; n < 6; ++n) acc[n] = (f32x4){0.f, 0.f, 0.f, 0.f};

#pragma unroll
    for (int s = 0; s < NS; ++s) {
        const short* wp = Wl + s * 32 + lh * 8;
#pragma unroll
        for (int n = 0; n < 6; ++n) {
            bf16x8 bf = *(const bf16x8*)(wp + (n * 16 + l15) * P);
            acc[n] = __builtin_amdgcn_mfma_f32_16x16x32_bf16(af[s], bf, acc[n], 0, 0, 0);
        }
    }

    // ---- epilogue: bias (regs) ----
    float cv[6][4];
#pragma unroll
    for (int n = 0; n < 6; ++n) {
        float b = bias[n * 16 + l15];
#pragma unroll
        for (int r = 0; r < 4; ++r) cv[n][r] = acc[n][r] + b;
    }
    int crow[4]; bool cok[4];
#pragma unroll
    for (int r = 0; r < 4; ++r) {
        crow[r] = base + w * 16 + lh * 4 + r;
        cok[r]  = crow[r] < NN;
    }

    // ---- C store via LDS bounce: Cl[64][100] -> row-major float4 stores ----
    __syncthreads();                       // all Wl (MFMA B) reads done
    float* Cl = (float*)Wl;                // 6400 floats used of 10304
#pragma unroll
    for (int n = 0; n < 6; ++n)
#pragma unroll
        for (int r = 0; r < 4; ++r)
            Cl[(w * 16 + lh * 4 + r) * 100 + n * 16 + l15] = cv[n][r];
    __syncthreads();
    {
        int lrow = t >> 2;                 // 0..63
        int q4   = t & 3;
        int grow = base + lrow;
        if (grow < NN) {
            float* o = out + (size_t)grow * HD;
            const float* cr = Cl + lrow * 100;
#pragma unroll
            for (int k = 0; k < 6; ++k) {
                int c4 = q4 + k * 4;       // 0..23
                *(float4*)(o + c4 * 4) = *(const float4*)(cr + c4 * 4);
            }
        }
    }

    if (MODE == 1) {
        float s[6], q[6];
#pragma unroll
        for (int n = 0; n < 6; ++n) {
            s[n] = 0.f; q[n] = 0.f;
#pragma unroll
            for (int r = 0; r < 4; ++r) {
                float v = cok[r] ? cv[n][r] : 0.f;
                s[n] += v; q[n] += v * v;
            }
        }
#pragma unroll
        for (int n = 0; n < 6; ++n) {
            s[n] += __shfl_xor(s[n], 16); s[n] += __shfl_xor(s[n], 32);
            q[n] += __shfl_xor(q[n], 16); q[n] += __shfl_xor(q[n], 32);
        }
        float* red0 = (float*)Wl + 6400;   // [4][96] (disjoint from Cl)
        float* red1 = red0 + 384;          // [4][96]
        if (lh == 0) {
#pragma unroll
            for (int n = 0; n < 6; ++n) {
                red0[w * 96 + n * 16 + l15] = s[n];
                red1[w * 96 + n * 16 + l15] = q[n];
            }
        }
        __syncthreads();
        if (t < HD) {
            float S = red0[t] + red0[96 + t] + red0[192 + t] + red0[288 + t];
            float Q = red1[t] + red1[96 + t] + red1[192 + t] + red1[288 + t];
            atomicAdd(&gsum[t], S);
            atomicAdd(&gsumsq[t], Q);
        }
    }

    if (MODE == 2) {
        float s[6];
#pragma unroll
        for (int n = 0; n < 6; ++n) {
            s[n] = 0.f;
#pragma unroll
            for (int r = 0; r < 4; ++r) s[n] += cok[r] ? cv[n][r] : 0.f;
        }
#pragma unroll
        for (int n = 0; n < 6; ++n) {
            s[n] += __shfl_xor(s[n], 16); s[n] += __shfl_xor(s[n], 32);
        }
        float rq[4];
#pragma unroll
        for (int r = 0; r < 4; ++r) {
            float v = 0.f;
#pragma unroll
            for (int n = 0; n < 6; ++n) v = fmaf(cv[n][r], cv[n][r], v);
            v += __shfl_xor(v, 1); v += __shfl_xor(v, 2);
            v += __shfl_xor(v, 4); v += __shfl_xor(v, 8);
            rq[r] = v;
        }
        float* red0 = (float*)Wl + 6400;   // [4][96] (disjoint from Cl)
        if (lh == 0) {
#pragma unroll
            for (int n = 0; n < 6; ++n) red0[w * 96 + n * 16 + l15] = s[n];
        }
        __syncthreads();
        if (t < HD) {
            float S = red0[t] + red0[96 + t] + red0[192 + t] + red0[288 + t];
            atomicAdd(&gcol[t], S);
        }
        if (l15 == 0) {
#pragma unroll
            for (int r = 0; r < 4; ++r)
                if (cok[r]) growss[crow[r]] = rq[r];
        }
    }
}

// ---------------- CSR build (sum 4 hist replicas; single cursor) ------------
__global__ __launch_bounds__(256) void scan_part1(const int* __restrict__ cnt,
                                                  int* __restrict__ bsum) {
    __shared__ int sh[256];
    int i = blockIdx.x * 256 + threadIdx.x;
    int t = threadIdx.x;
    int v = 0;
    if (i < NN)
        v = cnt[i] + cnt[NN + i] + cnt[2 * NN + i] + cnt[3 * NN + i];
    sh[t] = v;
    __syncthreads();
    for (int off = 128; off > 0; off >>= 1) {
        if (t < off) sh[t] += sh[t + off];
        __syncthreads();
    }
    if (t == 0) bsum[blockIdx.x] = sh[0];
}

__global__ __launch_bounds__(256) void scan_part2(int* __restrict__ bsum) {
    __shared__ int sh[256];
    int t = threadIdx.x;
    int v = (t < SCAN_NB) ? bsum[t] : 0;
    sh[t] = v;
    __syncthreads();
    for (int off = 1; off < 256; off <<= 1) {
        int u = sh[t];
        if (t >= off) u += sh[t - off];
        __syncthreads();
        sh[t] = u;
        __syncthreads();
    }
    if (t < SCAN_NB) bsum[t] = sh[t] - v;    // exclusive block offsets
}

__global__ __launch_bounds__(256) void scan_part3(int* __restrict__ cnt,
                                                  const int* __restrict__ bsum,
                                                  int* __restrict__ rowptr) {
    __shared__ int sh[256];
    int i = blockIdx.x * 256 + threadIdx.x;
    int t = threadIdx.x;
    int v = 0;
    if (i < NN)
        v = cnt[i] + cnt[NN + i] + cnt[2 * NN + i] + cnt[3 * NN + i];
    sh[t] = v;
    __syncthreads();
    for (int off = 1; off < 256; off <<= 1) {
        int u = sh[t];
        if (t >= off) u += sh[t - off];
        __syncthreads();
        sh[t] = u;
        __syncthreads();
    }
    int excl = sh[t] - v + bsum[blockIdx.x];
    if (i < NN) { rowptr[i] = excl; cnt[i] = excl; }   // cnt[0..NN): fill cursor
    if (i == NN - 1) rowptr[NN] = excl + v;
}

// fill with dst-range multipass, SINGLE cursor (round-15 A/B: replicated
// cursors cost 10%; replication only helps the hist side). Multipass
// dst-clustering kept (round-1 A/B: removing it cost 20% WRITE + 18% time).
__global__ __launch_bounds__(256) void fill_kernel(const int* __restrict__ ei,
                                                   int* __restrict__ cursor,
                                                   int* __restrict__ srcs, int E) {
    int t2 = blockIdx.x * 256 + threadIdx.x;
    int e0 = t2 * 2;
    int src[2], dst[2];
#pragma unroll
    for (int i = 0; i < 2; ++i) {
        int e = e0 + i;
        bool ok = e < E;
        dst[i] = ok ? ei[E + e] : -1;
        src[i] = ok ? ei[e] : 0;
    }
    for (int pass = 0; pass < 7; ++pass) {
#pragma unroll
        for (int i = 0; i < 2; ++i) {
            if (dst[i] >= 0 && (dst[i] >> 13) == pass) {
                int slot = atomicAdd(&cursor[dst[i]], 1);
                srcs[slot] = src[i];
            }
        }
    }
}

// -------- gather: z[i] = h0[i] + sum_{e:dst=i} h0[src_e] --------------------
__global__ __launch_bounds__(192) void gather_kernel(
    const float* __restrict__ h0, const int* __restrict__ rowptr,
    const int* __restrict__ srcs, float* __restrict__ z)
{
    const int tid = threadIdx.x;
    const int rl  = tid / 24;          // 0..7 local row
    const int c   = tid - rl * 24;     // 0..23 float4 lane
    const int row = blockIdx.x * 8 + rl;
    if (row >= NN) return;

    const int p0 = rowptr[row];
    const int p1 = rowptr[row + 1];

    float4 acc = ld4(h0 + (size_t)row * HD + c * 4);

    int p = p0;
    for (; p + 8 <= p1; p += 8) {
        int s0 = srcs[p + 0], s1 = srcs[p + 1], s2 = srcs[p + 2], s3 = srcs[p + 3];
        int s4 = srcs[p + 4], s5 = srcs[p + 5], s6 = srcs[p + 6], s7 = srcs[p + 7];
        float4 v0 = ld4(h0 + (size_t)s0 * HD + c * 4);
        float4 v1 = ld4(h0 + (size_t)s1 * HD + c * 4);
        float4 v2 = ld4(h0 + (size_t)s2 * HD + c * 4);
        float4 v3 = ld4(h0 + (size_t)s3 * HD + c * 4);
        float4 v4 = ld4(h0 + (size_t)s4 * HD + c * 4);
        float4 v5 = ld4(h0 + (size_t)s5 * HD + c * 4);
        float4 v6 = ld4(h0 + (size_t)s6 * HD + c * 4);
        float4 v7 = ld4(h0 + (size_t)s7 * HD + c * 4);
        acc = add4(acc, add4(add4(add4(v0, v1), add4(v2, v3)),
                             add4(add4(v4, v5), add4(v6, v7))));
    }
    for (; p + 4 <= p1; p += 4) {
        int s0 = srcs[p + 0], s1 = srcs[p + 1], s2 = srcs[p + 2], s3 = srcs[p + 3];
        float4 v0 = ld4(h0 + (size_t)s0 * HD + c * 4);
        float4 v1 = ld4(h0 + (size_t)s1 * HD + c * 4);
        float4 v2 = ld4(h0 + (size_t)s2 * HD + c * 4);
        float4 v3 = ld4(h0 + (size_t)s3 * HD + c * 4);
        acc = add4(acc, add4(add4(v0, v1), add4(v2, v3)));
    }
    for (; p < p1; ++p)
        acc = add4(acc, ld4(h0 + (size_t)srcs[p] * HD + c * 4));

    *(float4*)(z + (size_t)row * HD + c * 4) = acc;
}

__global__ void bn_finalize_kernel(const float* __restrict__ sum, const float* __restrict__ sumsq,
                                   const float* __restrict__ gamma, const float* __restrict__ beta,
                                   float* __restrict__ scale, float* __restrict__ shift)
{
    int f = threadIdx.x;
    if (f < HD) {
        float mean = sum[f] * (1.0f / NN);
        float var  = fmaxf(sumsq[f] * (1.0f / NN) - mean * mean, 0.0f);
        float rstd = rsqrtf(var + BN_EPS);
        float sc = rstd * gamma[f];
        scale[f] = sc;
        shift[f] = beta[f] - mean * sc;
    }
}

// ---------------- PairNorm: streaming float4, in place ----------------
__global__ __launch_bounds__(256) void pn_kernel(float* l1, const float* __restrict__ colsum,
                                                 const float* __restrict__ rowss)
{
    int idx = blockIdx.x * 256 + threadIdx.x;   // float4 index
    if (idx >= NN * 24) return;
    int row = idx / 24;
    int q = idx - row * 24;
    float rs = rsqrtf(1e-6f + rowss[row]);
    float4 v = ld4(l1 + (size_t)idx * 4);
    float4 cm = ld4(colsum + q * 4);
    v.x = PN_SCALE * v.x * rs - cm.x * (1.0f / NN);
    v.y = PN_SCALE * v.y * rs - cm.y * (1.0f / NN);
    v.z = PN_SCALE * v.z * rs - cm.z * (1.0f / NN);
    v.w = PN_SCALE * v.w * rs - cm.w * (1.0f / NN);
    *(float4*)(l1 + (size_t)idx * 4) = v;
}

extern "C" void kernel_launch(void* const* d_in, const int* in_sizes, int n_in,
                              void* d_out, int out_size, void* d_ws, size_t ws_size,
                              hipStream_t stream) {
    const float* x     = (const float*)d_in[0];
    const int*   ei    = (const int*)d_in[1];
    const float* W0    = (const float*)d_in[2];
    const float* b0    = (const float*)d_in[3];
    const float* W1    = (const float*)d_in[4];
    const float* b1    = (const float*)d_in[5];
    const float* gamma = (const float*)d_in[6];
    const float* beta  = (const float*)d_in[7];
    const float* W2    = (const float*)d_in[8];
    const float* b2    = (const float*)d_in[9];

    float* out_l1 = (float*)d_out;                 // [N,96]: z -> h -> l1 (in place)
    float* out_h0 = out_l1 + (size_t)NN * HD;      // [N,96]: h0 output

    float* stats   = (float*)d_ws;
    float* s_sum   = stats;            // 96
    float* s_sumsq = stats + HD;       // 96
    float* s_col   = stats + 2 * HD;   // 96
    float* s_scale = stats + 288;      // 96
    float* s_shift = stats + 384;      // 96
    float* rowss = stats + 1024;
    int* cnt    = (int*)(rowss + NN);              // [NREP][NN] hist; [0..NN) cursor
    int* rowptr = cnt + NREP * NN;
    int* bsum   = rowptr + NN + 2;
    int* srcs   = bsum + 256;

    const int E = in_sizes[1] / 2;                 // 800000
    const int GB = (NN + 63) / 64;                 // 782

    zero_kernel<<<(1024 + NREP * NN + 255) / 256, 256, 0, stream>>>(stats, cnt);
    // 1) h0 = x @ W0^T + b0 (MFMA), replicated edge histogram fused
    gemm_mfma<IN_DIM, 0><<<GB, 256, 0, stream>>>(x, W0, b0, out_h0, nullptr, nullptr,
                                                 nullptr, nullptr, nullptr, nullptr,
                                                 ei, cnt, E);
    // 2) CSR build: replica-summing scan -> multipass fill w/ single cursor
    scan_part1<<<SCAN_NB, 256, 0, stream>>>(cnt, bsum);
    scan_part2<<<1, 256, 0, stream>>>(bsum);
    scan_part3<<<SCAN_NB, 256, 0, stream>>>(cnt, bsum, rowptr);
    fill_kernel<<<(E / 2 + 255) / 256, 256, 0, stream>>>(ei, cnt, srcs, E);
    // 3) gather: z = h0 + segment_sum(h0[src])
    gather_kernel<<<(NN + 7) / 8, 192, 0, stream>>>(out_h0, rowptr, srcs, out_l1);
    // 4) h = z @ W1^T + b1 (in place, MFMA) + fused BN stats
    gemm_mfma<HD, 1><<<GB, 256, 0, stream>>>(out_l1, W1, b1, out_l1, nullptr, nullptr,
                                             s_sum, s_sumsq, nullptr, nullptr,
                                             nullptr, nullptr, 0);
    bn_finalize_kernel<<<1, 128, 0, stream>>>(s_sum, s_sumsq, gamma, beta, s_scale, s_shift);
    // 5) l1 = relu(bn(h)) @ W2^T + b2 (in place, MFMA) + fused PN stats
    gemm_mfma<HD, 2><<<GB, 256, 0, stream>>>(out_l1, W2, b2, out_l1, s_scale, s_shift,
                                             nullptr, nullptr, s_col, rowss,
                                             nullptr, nullptr, 0);
    // 6) PairNorm finalize (streaming, in place)
    pn_kernel<<<(NN * 24 + 255) / 256, 256, 0, stream>>>(out_l1, s_col, rowss);
}

// Round 17
// 287.021 us; speedup vs baseline: 1.0238x; 1.0238x over previous
//
#include <hip/hip_runtime.h>

#define NN 50000
#define IN_DIM 128
#define HD 96
#define BN_EPS 1e-5f
#define PN_SCALE 20.0f
#define SCAN_NB 196   // ceil(50000/256)
#define NREP 4        // hist replicas (hist only; fill uses a single cursor)

using bf16x8 = __attribute__((ext_vector_type(8))) short;
using f32x4  = __attribute__((ext_vector_type(4))) float;

__device__ __forceinline__ float4 ld4(const float* p) { return *(const float4*)p; }
__device__ __forceinline__ float4 add4(float4 a, float4 b) {
    return make_float4(a.x + b.x, a.y + b.y, a.z + b.z, a.w + b.w);
}

// fp32 -> bf16 round-to-nearest-even (bit trick; no builtin dependency)
__device__ __forceinline__ short bfr(float f) {
    unsigned u = __float_as_uint(f);
    unsigned r = u + 0x7fffu + ((u >> 16) & 1u);
    return (short)(r >> 16);
}
__device__ __forceinline__ float bf2f(unsigned short s) {
    return __uint_as_float((unsigned)s << 16);
}
__device__ __forceinline__ bf16x8 cvt8(float4 a, float4 b) {
    bf16x8 r;
    r[0] = bfr(a.x); r[1] = bfr(a.y); r[2] = bfr(a.z); r[3] = bfr(a.w);
    r[4] = bfr(b.x); r[5] = bfr(b.y); r[6] = bfr(b.z); r[7] = bfr(b.w);
    return r;
}

// ---------------- zero stats + replicated CSR counters ----------------
__global__ void zero_kernel(float* stats, int* cnt) {
    int i = blockIdx.x * blockDim.x + threadIdx.x;
    if (i < 1024) stats[i] = 0.0f;
    int j = i - 1024;
    if (j >= 0 && j < NREP * NN) cnt[j] = 0;
}

// ---------------- MFMA GEMM: C[N,96] = act(A[N,K]) @ W[96,K]^T + b ----------
// Round-16 A/B: LDS-bounce on all modes cost ~2-3us/gemm with no visible WRITE
// benefit -> bounce kept ONLY in MODE 0, where it doubles as the coalesced
// writer of the bf16 h0 sidecar (out_bf) that halves gather's random-read
// footprint (384B -> 192B per row). MODE 1/2 revert to direct scalar stores
// (round-15 structure). Hist stays 4-replica (round-15: helped gemm0).
template<int K, int MODE>
__global__ __launch_bounds__(256) void gemm_mfma(
    const float* A, const float* __restrict__ W, const float* __restrict__ bias,
    float* out, unsigned short* __restrict__ out_bf,
    const float* __restrict__ scale, const float* __restrict__ shift,
    float* __restrict__ gsum, float* __restrict__ gsumsq,
    float* __restrict__ gcol, float* __restrict__ growss,
    const int* __restrict__ ei, int* __restrict__ hist_cnt, int E)
{
    constexpr int P     = K + 8;   // bf16 pitch: 16B-aligned rows, spread banks
    constexpr int NS    = K / 32;  // K-steps
    constexpr int KD4   = K / 4;   // dword4 chunks per W row
    constexpr int WITER = (96 * KD4) / 256;   // 12 (K=128) / 9 (K=96)
    constexpr int WL_SH  = 96 * P;            // shorts actually used
    constexpr int WL_TOT = (20608 > WL_SH) ? 20608 : WL_SH;  // 41216 B
    __shared__ short Wl[WL_TOT];   // LDS caps occupancy at 3 blocks/CU (= grid)

    const int t    = threadIdx.x;
    const int l    = t & 63;
    const int w    = t >> 6;       // wave 0..3
    const int l15  = l & 15;
    const int lh   = l >> 4;       // 0..3
    const int base = blockIdx.x * 64;

    const int  arow = base + w * 16 + l15;
    const bool aok  = arow < NN;
    const float* Ap = A + (size_t)arow * K + lh * 8;
    const float4 Z4 = make_float4(0.f, 0.f, 0.f, 0.f);

    // ---- cluster ALL global loads up front ----
    float4 pa[2 * NS];
#pragma unroll
    for (int s = 0; s < NS; ++s) {
        pa[2 * s]     = aok ? ld4(Ap + s * 32)     : Z4;
        pa[2 * s + 1] = aok ? ld4(Ap + s * 32 + 4) : Z4;
    }
    float4 wv[WITER];
#pragma unroll
    for (int i = 0; i < WITER; ++i) {
        int c = t + i * 256;
        int row = c / KD4, kq = c - row * KD4;
        wv[i] = ld4(W + (size_t)row * K + kq * 4);
    }
    float4 scv[2 * NS], shv[2 * NS];
    if (MODE == 2) {
#pragma unroll
        for (int s = 0; s < 2 * NS; ++s) {
            scv[s] = ld4(scale + (s >> 1) * 32 + lh * 8 + (s & 1) * 4);
            shv[s] = ld4(shift + (s >> 1) * 32 + lh * 8 + (s & 1) * 4);
        }
    }

    if (MODE == 0) {               // fused histogram: 4 edges/thread, replicated
        int e0 = (blockIdx.x * 256 + t) * 4;   // e0 % 4 == 0 -> replica = i
        if (e0 + 4 <= E) {
            int4 d4 = *(const int4*)(ei + E + e0);
            atomicAdd(&hist_cnt[0 * NN + d4.x], 1);
            atomicAdd(&hist_cnt[1 * NN + d4.y], 1);
            atomicAdd(&hist_cnt[2 * NN + d4.z], 1);
            atomicAdd(&hist_cnt[3 * NN + d4.w], 1);
        } else {
            for (int i = 0; i < 4; ++i) {
                int e = e0 + i;
                if (e < E) atomicAdd(&hist_cnt[(e & 3) * NN + ei[E + e]], 1);
            }
        }
    }

    // ---- convert A early (waits only on A loads; frees 2*NS float4s) ----
    bf16x8 af[NS];
#pragma unroll
    for (int s = 0; s < NS; ++s) {
        float4 q0 = pa[2 * s], q1 = pa[2 * s + 1];
        if (MODE == 2) {
            float4 sc0 = scv[2 * s], sh0 = shv[2 * s];
            float4 sc1 = scv[2 * s + 1], sh1 = shv[2 * s + 1];
            q0.x = fmaxf(q0.x * sc0.x + sh0.x, 0.f);
            q0.y = fmaxf(q0.y * sc0.y + sh0.y, 0.f);
            q0.z = fmaxf(q0.z * sc0.z + sh0.z, 0.f);
            q0.w = fmaxf(q0.w * sc0.w + sh0.w, 0.f);
            q1.x = fmaxf(q1.x * sc1.x + sh1.x, 0.f);
            q1.y = fmaxf(q1.y * sc1.y + sh1.y, 0.f);
            q1.z = fmaxf(q1.z * sc1.z + sh1.z, 0.f);
            q1.w = fmaxf(q1.w * sc1.w + sh1.w, 0.f);
        }
        af[s] = cvt8(q0, q1);
    }

    // ---- convert + stage W -> bf16 LDS ----
#pragma unroll
    for (int i = 0; i < WITER; ++i) {
        int c = t + i * 256;
        int row = c / KD4, kq = c - row * KD4;
        short4 s4v;
        s4v.x = bfr(wv[i].x); s4v.y = bfr(wv[i].y);
        s4v.z = bfr(wv[i].z); s4v.w = bfr(wv[i].w);
        *(short4*)(Wl + row * P + kq * 4) = s4v;
    }
    __syncthreads();

    f32x4 acc[6];
#pragma unroll
    for (int n = 0; n < 6; ++n) acc[n] = (f32x4){0.f, 0.f, 0.f, 0.f};

#pragma unroll
    for (int s = 0; s < NS; ++s) {
        const short* wp = Wl + s * 32 + lh * 8;
#pragma unroll
        for (int n = 0; n < 6; ++n) {
            bf16x8 bf = *(const bf16x8*)(wp + (n * 16 + l15) * P);
            acc[n] = __builtin_amdgcn_mfma_f32_16x16x32_bf16(af[s], bf, acc[n], 0, 0, 0);
        }
    }

    // ---- epilogue: bias (regs) ----
    float cv[6][4];
#pragma unroll
    for (int n = 0; n < 6; ++n) {
        float b = bias[n * 16 + l15];
#pragma unroll
        for (int r = 0; r < 4; ++r) cv[n][r] = acc[n][r] + b;
    }
    int crow[4]; bool cok[4];
#pragma unroll
    for (int r = 0; r < 4; ++r) {
        crow[r] = base + w * 16 + lh * 4 + r;
        cok[r]  = crow[r] < NN;
    }

    if (MODE == 0) {
        // C store via LDS bounce + coalesced bf16 sidecar for gather
        __syncthreads();                   // all Wl (MFMA B) reads done
        float* Cl = (float*)Wl;            // [64][100]
#pragma unroll
        for (int n = 0; n < 6; ++n)
#pragma unroll
            for (int r = 0; r < 4; ++r)
                Cl[(w * 16 + lh * 4 + r) * 100 + n * 16 + l15] = cv[n][r];
        __syncthreads();
        int lrow = t >> 2;                 // 0..63
        int q4   = t & 3;
        int grow = base + lrow;
        if (grow < NN) {
            float* o = out + (size_t)grow * HD;
            unsigned short* ob = out_bf + (size_t)grow * HD;
            const float* cr = Cl + lrow * 100;
#pragma unroll
            for (int k = 0; k < 6; ++k) {
                int c4 = q4 + k * 4;       // 0..23
                float4 v = *(const float4*)(cr + c4 * 4);
                *(float4*)(o + c4 * 4) = v;
                ushort4 sv;
                sv.x = (unsigned short)bfr(v.x);
                sv.y = (unsigned short)bfr(v.y);
                sv.z = (unsigned short)bfr(v.z);
                sv.w = (unsigned short)bfr(v.w);
                *(ushort4*)(ob + c4 * 4) = sv;
            }
        }
    } else {
        // direct scalar stores (round-15 structure; bounce cost ~2-3us/gemm)
#pragma unroll
        for (int r = 0; r < 4; ++r) {
            if (cok[r]) {
                float* o = out + (size_t)crow[r] * HD + l15;
#pragma unroll
                for (int n = 0; n < 6; ++n) o[n * 16] = cv[n][r];
            }
        }
    }

    if (MODE == 1) {
        float s[6], q[6];
#pragma unroll
        for (int n = 0; n < 6; ++n) {
            s[n] = 0.f; q[n] = 0.f;
#pragma unroll
            for (int r = 0; r < 4; ++r) {
                float v = cok[r] ? cv[n][r] : 0.f;
                s[n] += v; q[n] += v * v;
            }
        }
#pragma unroll
        for (int n = 0; n < 6; ++n) {
            s[n] += __shfl_xor(s[n], 16); s[n] += __shfl_xor(s[n], 32);
            q[n] += __shfl_xor(q[n], 16); q[n] += __shfl_xor(q[n], 32);
        }
        __syncthreads();                       // Wl dead everywhere; overlay
        float* red0 = (float*)Wl;              // [4][96]
        float* red1 = red0 + 384;              // [4][96]
        if (lh == 0) {
#pragma unroll
            for (int n = 0; n < 6; ++n) {
                red0[w * 96 + n * 16 + l15] = s[n];
                red1[w * 96 + n * 16 + l15] = q[n];
            }
        }
        __syncthreads();
        if (t < HD) {
            float S = red0[t] + red0[96 + t] + red0[192 + t] + red0[288 + t];
            float Q = red1[t] + red1[96 + t] + red1[192 + t] + red1[288 + t];
            atomicAdd(&gsum[t], S);
            atomicAdd(&gsumsq[t], Q);
        }
    }

    if (MODE == 2) {
        float s[6];
#pragma unroll
        for (int n = 0; n < 6; ++n) {
            s[n] = 0.f;
#pragma unroll
            for (int r = 0; r < 4; ++r) s[n] += cok[r] ? cv[n][r] : 0.f;
        }
#pragma unroll
        for (int n = 0; n < 6; ++n) {
            s[n] += __shfl_xor(s[n], 16); s[n] += __shfl_xor(s[n], 32);
        }
        float rq[4];
#pragma unroll
        for (int r = 0; r < 4; ++r) {
            float v = 0.f;
#pragma unroll
            for (int n = 0; n < 6; ++n) v = fmaf(cv[n][r], cv[n][r], v);
            v += __shfl_xor(v, 1); v += __shfl_xor(v, 2);
            v += __shfl_xor(v, 4); v += __shfl_xor(v, 8);
            rq[r] = v;
        }
        __syncthreads();                       // Wl dead; overlay
        float* red0 = (float*)Wl;              // [4][96]
        if (lh == 0) {
#pragma unroll
            for (int n = 0; n < 6; ++n) red0[w * 96 + n * 16 + l15] = s[n];
        }
        __syncthreads();
        if (t < HD) {
            float S = red0[t] + red0[96 + t] + red0[192 + t] + red0[288 + t];
            atomicAdd(&gcol[t], S);
        }
        if (l15 == 0) {
#pragma unroll
            for (int r = 0; r < 4; ++r)
                if (cok[r]) growss[crow[r]] = rq[r];
        }
    }
}

// ---------------- CSR build (sum 4 hist replicas; single cursor) ------------
__global__ __launch_bounds__(256) void scan_part1(const int* __restrict__ cnt,
                                                  int* __restrict__ bsum) {
    __shared__ int sh[256];
    int i = blockIdx.x * 256 + threadIdx.x;
    int t = threadIdx.x;
    int v = 0;
    if (i < NN)
        v = cnt[i] + cnt[NN + i] + cnt[2 * NN + i] + cnt[3 * NN + i];
    sh[t] = v;
    __syncthreads();
    for (int off = 128; off > 0; off >>= 1) {
        if (t < off) sh[t] += sh[t + off];
        __syncthreads();
    }
    if (t == 0) bsum[blockIdx.x] = sh[0];
}

__global__ __launch_bounds__(256) void scan_part2(int* __restrict__ bsum) {
    __shared__ int sh[256];
    int t = threadIdx.x;
    int v = (t < SCAN_NB) ? bsum[t] : 0;
    sh[t] = v;
    __syncthreads();
    for (int off = 1; off < 256; off <<= 1) {
        int u = sh[t];
        if (t >= off) u += sh[t - off];
        __syncthreads();
        sh[t] = u;
        __syncthreads();
    }
    if (t < SCAN_NB) bsum[t] = sh[t] - v;    // exclusive block offsets
}

__global__ __launch_bounds__(256) void scan_part3(int* __restrict__ cnt,
                                                  const int* __restrict__ bsum,
                                                  int* __restrict__ rowptr) {
    __shared__ int sh[256];
    int i = blockIdx.x * 256 + threadIdx.x;
    int t = threadIdx.x;
    int v = 0;
    if (i < NN)
        v = cnt[i] + cnt[NN + i] + cnt[2 * NN + i] + cnt[3 * NN + i];
    sh[t] = v;
    __syncthreads();
    for (int off = 1; off < 256; off <<= 1) {
        int u = sh[t];
        if (t >= off) u += sh[t - off];
        __syncthreads();
        sh[t] = u;
        __syncthreads();
    }
    int excl = sh[t] - v + bsum[blockIdx.x];
    if (i < NN) { rowptr[i] = excl; cnt[i] = excl; }   // cnt[0..NN): fill cursor
    if (i == NN - 1) rowptr[NN] = excl + v;
}

// fill with dst-range multipass, single cursor (round-15 A/B: replicated
// cursors cost 10%). Multipass dst-clustering kept (round-1 A/B).
__global__ __launch_bounds__(256) void fill_kernel(const int* __restrict__ ei,
                                                   int* __restrict__ cursor,
                                                   int* __restrict__ srcs, int E) {
    int t2 = blockIdx.x * 256 + threadIdx.x;
    int e0 = t2 * 2;
    int src[2], dst[2];
#pragma unroll
    for (int i = 0; i < 2; ++i) {
        int e = e0 + i;
        bool ok = e < E;
        dst[i] = ok ? ei[E + e] : -1;
        src[i] = ok ? ei[e] : 0;
    }
    for (int pass = 0; pass < 7; ++pass) {
#pragma unroll
        for (int i = 0; i < 2; ++i) {
            if (dst[i] >= 0 && (dst[i] >> 13) == pass) {
                int slot = atomicAdd(&cursor[dst[i]], 1);
                srcs[slot] = src[i];
            }
        }
    }
}

// -------- gather: z[i] = h0[i] + sum_{e:dst=i} h0b[src_e] (bf16 sidecar) ----
// Self row in exact fp32; neighbor rows from the bf16 sidecar (192B/row vs
// 384B -> halves random-read footprint; 9.6MB table L2-caches ~2x better).
__global__ __launch_bounds__(192) void gather_kernel(
    const float* __restrict__ h0, const unsigned short* __restrict__ h0b,
    const int* __restrict__ rowptr, const int* __restrict__ srcs,
    float* __restrict__ z)
{
    const int tid = threadIdx.x;
    const int rl  = tid / 24;          // 0..7 local row
    const int c   = tid - rl * 24;     // 0..23 quad lane
    const int row = blockIdx.x * 8 + rl;
    if (row >= NN) return;

    const int p0 = rowptr[row];
    const int p1 = rowptr[row + 1];

    float4 acc = ld4(h0 + (size_t)row * HD + c * 4);

    int p = p0;
    for (; p + 8 <= p1; p += 8) {
        int s0 = srcs[p + 0], s1 = srcs[p + 1], s2 = srcs[p + 2], s3 = srcs[p + 3];
        int s4 = srcs[p + 4], s5 = srcs[p + 5], s6 = srcs[p + 6], s7 = srcs[p + 7];
        ushort4 v0 = *(const ushort4*)(h0b + (size_t)s0 * HD + c * 4);
        ushort4 v1 = *(const ushort4*)(h0b + (size_t)s1 * HD + c * 4);
        ushort4 v2 = *(const ushort4*)(h0b + (size_t)s2 * HD + c * 4);
        ushort4 v3 = *(const ushort4*)(h0b + (size_t)s3 * HD + c * 4);
        ushort4 v4 = *(const ushort4*)(h0b + (size_t)s4 * HD + c * 4);
        ushort4 v5 = *(const ushort4*)(h0b + (size_t)s5 * HD + c * 4);
        ushort4 v6 = *(const ushort4*)(h0b + (size_t)s6 * HD + c * 4);
        ushort4 v7 = *(const ushort4*)(h0b + (size_t)s7 * HD + c * 4);
        acc.x += bf2f(v0.x) + bf2f(v1.x) + bf2f(v2.x) + bf2f(v3.x)
               + bf2f(v4.x) + bf2f(v5.x) + bf2f(v6.x) + bf2f(v7.x);
        acc.y += bf2f(v0.y) + bf2f(v1.y) + bf2f(v2.y) + bf2f(v3.y)
               + bf2f(v4.y) + bf2f(v5.y) + bf2f(v6.y) + bf2f(v7.y);
        acc.z += bf2f(v0.z) + bf2f(v1.z) + bf2f(v2.z) + bf2f(v3.z)
               + bf2f(v4.z) + bf2f(v5.z) + bf2f(v6.z) + bf2f(v7.z);
        acc.w += bf2f(v0.w) + bf2f(v1.w) + bf2f(v2.w) + bf2f(v3.w)
               + bf2f(v4.w) + bf2f(v5.w) + bf2f(v6.w) + bf2f(v7.w);
    }
    for (; p < p1; ++p) {
        ushort4 v = *(const ushort4*)(h0b + (size_t)srcs[p] * HD + c * 4);
        acc.x += bf2f(v.x); acc.y += bf2f(v.y);
        acc.z += bf2f(v.z); acc.w += bf2f(v.w);
    }

    *(float4*)(z + (size_t)row * HD + c * 4) = acc;
}

__global__ void bn_finalize_kernel(const float* __restrict__ sum, const float* __restrict__ sumsq,
                                   const float* __restrict__ gamma, const float* __restrict__ beta,
                                   float* __restrict__ scale, float* __restrict__ shift)
{
    int f = threadIdx.x;
    if (f < HD) {
        float mean = sum[f] * (1.0f / NN);
        float var  = fmaxf(sumsq[f] * (1.0f / NN) - mean * mean, 0.0f);
        float rstd = rsqrtf(var + BN_EPS);
        float sc = rstd * gamma[f];
        scale[f] = sc;
        shift[f] = beta[f] - mean * sc;
    }
}

// ---------------- PairNorm: streaming float4, in place ----------------
__global__ __launch_bounds__(256) void pn_kernel(float* l1, const float* __restrict__ colsum,
                                                 const float* __restrict__ rowss)
{
    int idx = blockIdx.x * 256 + threadIdx.x;   // float4 index
    if (idx >= NN * 24) return;
    int row = idx / 24;
    int q = idx - row * 24;
    float rs = rsqrtf(1e-6f + rowss[row]);
    float4 v = ld4(l1 + (size_t)idx * 4);
    float4 cm = ld4(colsum + q * 4);
    v.x = PN_SCALE * v.x * rs - cm.x * (1.0f / NN);
    v.y = PN_SCALE * v.y * rs - cm.y * (1.0f / NN);
    v.z = PN_SCALE * v.z * rs - cm.z * (1.0f / NN);
    v.w = PN_SCALE * v.w * rs - cm.w * (1.0f / NN);
    *(float4*)(l1 + (size_t)idx * 4) = v;
}

extern "C" void kernel_launch(void* const* d_in, const int* in_sizes, int n_in,
                              void* d_out, int out_size, void* d_ws, size_t ws_size,
                              hipStream_t stream) {
    const float* x     = (const float*)d_in[0];
    const int*   ei    = (const int*)d_in[1];
    const float* W0    = (const float*)d_in[2];
    const float* b0    = (const float*)d_in[3];
    const float* W1    = (const float*)d_in[4];
    const float* b1    = (const float*)d_in[5];
    const float* gamma = (const float*)d_in[6];
    const float* beta  = (const float*)d_in[7];
    const float* W2    = (const float*)d_in[8];
    const float* b2    = (const float*)d_in[9];

    float* out_l1 = (float*)d_out;                 // [N,96]: z -> h -> l1 (in place)
    float* out_h0 = out_l1 + (size_t)NN * HD;      // [N,96]: h0 output

    float* stats   = (float*)d_ws;
    float* s_sum   = stats;            // 96
    float* s_sumsq = stats + HD;       // 96
    float* s_col   = stats + 2 * HD;   // 96
    float* s_scale = stats + 288;      // 96
    float* s_shift = stats + 384;      // 96
    float* rowss = stats + 1024;
    int* cnt    = (int*)(rowss + NN);              // [NREP][NN] hist; [0..NN) cursor
    int* rowptr = cnt + NREP * NN;
    int* bsum   = rowptr + NN + 2;
    int* srcs   = bsum + 256;
    unsigned short* h0b =
        (unsigned short*)(((uintptr_t)(srcs + 800000) + 15) & ~(uintptr_t)15);

    const int E = in_sizes[1] / 2;                 // 800000
    const int GB = (NN + 63) / 64;                 // 782

    zero_kernel<<<(1024 + NREP * NN + 255) / 256, 256, 0, stream>>>(stats, cnt);
    // 1) h0 = x @ W0^T + b0 (MFMA) + bf16 sidecar + replicated edge histogram
    gemm_mfma<IN_DIM, 0><<<GB, 256, 0, stream>>>(x, W0, b0, out_h0, h0b,
                                                 nullptr, nullptr,
                                                 nullptr, nullptr, nullptr, nullptr,
                                                 ei, cnt, E);
    // 2) CSR build: replica-summing scan -> multipass fill w/ single cursor
    scan_part1<<<SCAN_NB, 256, 0, stream>>>(cnt, bsum);
    scan_part2<<<1, 256, 0, stream>>>(bsum);
    scan_part3<<<SCAN_NB, 256, 0, stream>>>(cnt, bsum, rowptr);
    fill_kernel<<<(E / 2 + 255) / 256, 256, 0, stream>>>(ei, cnt, srcs, E);
    // 3) gather: z = h0 + segment_sum(h0b[src]) (bf16 sidecar reads)
    gather_kernel<<<(NN + 7) / 8, 192, 0, stream>>>(out_h0, h0b, rowptr, srcs, out_l1);
    // 4) h = z @ W1^T + b1 (in place, MFMA) + fused BN stats
    gemm_mfma<HD, 1><<<GB, 256, 0, stream>>>(out_l1, W1, b1, out_l1, nullptr,
                                             nullptr, nullptr,
                                             s_sum, s_sumsq, nullptr, nullptr,
                                             nullptr, nullptr, 0);
    bn_finalize_kernel<<<1, 128, 0, stream>>>(s_sum, s_sumsq, gamma, beta, s_scale, s_shift);
    // 5) l1 = relu(bn(h)) @ W2^T + b2 (in place, MFMA) + fused PN stats
    gemm_mfma<HD, 2><<<GB, 256, 0, stream>>>(out_l1, W2, b2, out_l1, nullptr,
                                             s_scale, s_shift,
                                             nullptr, nullptr, s_col, rowss,
                                             nullptr, nullptr, 0);
    // 6) PairNorm finalize (streaming, in place)
    pn_kernel<<<(NN * 24 + 255) / 256, 256, 0, stream>>>(out_l1, s_col, rowss);
}

// Round 18
// 282.107 us; speedup vs baseline: 1.0416x; 1.0174x over previous
//
#include <hip/hip_runtime.h>

#define NN 50000
#define IN_DIM 128
#define HD 96
#define BN_EPS 1e-5f
#define PN_SCALE 20.0f
#define SCAN_NB 196   // ceil(50000/256)
#define NREP 4        // hist replicas (hist only; fill uses a single cursor)

using bf16x8 = __attribute__((ext_vector_type(8))) short;
using f32x4  = __attribute__((ext_vector_type(4))) float;

__device__ __forceinline__ float4 ld4(const float* p) { return *(const float4*)p; }

// fp32 -> bf16 round-to-nearest-even (bit trick; no builtin dependency)
__device__ __forceinline__ short bfr(float f) {
    unsigned u = __float_as_uint(f);
    unsigned r = u + 0x7fffu + ((u >> 16) & 1u);
    return (short)(r >> 16);
}
__device__ __forceinline__ float bf2f(unsigned short s) {
    return __uint_as_float((unsigned)s << 16);
}
__device__ __forceinline__ bf16x8 cvt8(float4 a, float4 b) {
    bf16x8 r;
    r[0] = bfr(a.x); r[1] = bfr(a.y); r[2] = bfr(a.z); r[3] = bfr(a.w);
    r[4] = bfr(b.x); r[5] = bfr(b.y); r[6] = bfr(b.z); r[7] = bfr(b.w);
    return r;
}

// ---------------- zero stats + replicated CSR counters ----------------
__global__ void zero_kernel(float* stats, int* cnt) {
    int i = blockIdx.x * blockDim.x + threadIdx.x;
    if (i < 1024) stats[i] = 0.0f;
    int j = i - 1024;
    if (j >= 0 && j < NREP * NN) cnt[j] = 0;
}

// ---------------- MFMA GEMM: C[N,96] = act(A[N,K]) @ W[96,K]^T + b ----------
// Round-17 resolution: gemms' 24MB WRITE excess = cross-dispatch dirty-line
// eviction attribution (survives fully-coalesced bounce stores) -> stop
// polishing stores. Round-18: MODE 1 fuses the GATHER (z = h0 + sum h0b[src])
// into its A-fragment prep -- z is never materialized (saves the ~40us gather
// dispatch + 19.2MB write + 19.2MB read). Lane (l15,lh) owns row w*16+l15,
// k-slice lh*8: self slice from fp32 h0, neighbors from bf16 sidecar in
// 4-edge batches (12 independent 16B loads in flight). MODE 0 writes the
// sidecar via its LDS bounce; MODE 2 unchanged in-place (wave-disjoint rows).
template<int K, int MODE>
__global__ __launch_bounds__(256) void gemm_mfma(
    const float* A, const float* __restrict__ W, const float* __restrict__ bias,
    float* out, unsigned short* __restrict__ out_bf,
    const float* __restrict__ scale, const float* __restrict__ shift,
    float* __restrict__ gsum, float* __restrict__ gsumsq,
    float* __restrict__ gcol, float* __restrict__ growss,
    const int* __restrict__ ei, int* __restrict__ hist_cnt, int E,
    const unsigned short* __restrict__ g_h0b, const int* __restrict__ g_rowptr,
    const int* __restrict__ g_srcs)
{
    constexpr int P     = K + 8;   // bf16 pitch: 16B-aligned rows, spread banks
    constexpr int NS    = K / 32;  // K-steps
    constexpr int KD4   = K / 4;   // dword4 chunks per W row
    constexpr int WITER = (96 * KD4) / 256;   // 12 (K=128) / 9 (K=96)
    constexpr int WL_SH  = 96 * P;            // shorts actually used
    constexpr int WL_TOT = (20608 > WL_SH) ? 20608 : WL_SH;  // 41216 B
    __shared__ short Wl[WL_TOT];   // LDS caps occupancy at 3 blocks/CU (= grid)

    const int t    = threadIdx.x;
    const int l    = t & 63;
    const int w    = t >> 6;       // wave 0..3
    const int l15  = l & 15;
    const int lh   = l >> 4;       // 0..3
    const int base = blockIdx.x * 64;

    const int  arow = base + w * 16 + l15;
    const bool aok  = arow < NN;
    const float* Ap = A + (size_t)arow * K + lh * 8;
    const float4 Z4 = make_float4(0.f, 0.f, 0.f, 0.f);

    // ---- cluster global loads up front ----
    float4 pa[2 * NS];
#pragma unroll
    for (int s = 0; s < NS; ++s) {
        pa[2 * s]     = aok ? ld4(Ap + s * 32)     : Z4;
        pa[2 * s + 1] = aok ? ld4(Ap + s * 32 + 4) : Z4;
    }
    float4 wv[WITER];
#pragma unroll
    for (int i = 0; i < WITER; ++i) {
        int c = t + i * 256;
        int row = c / KD4, kq = c - row * KD4;
        wv[i] = ld4(W + (size_t)row * K + kq * 4);
    }
    float4 scv[2 * NS], shv[2 * NS];
    if (MODE == 2) {
#pragma unroll
        for (int s = 0; s < 2 * NS; ++s) {
            scv[s] = ld4(scale + (s >> 1) * 32 + lh * 8 + (s & 1) * 4);
            shv[s] = ld4(shift + (s >> 1) * 32 + lh * 8 + (s & 1) * 4);
        }
    }

    if (MODE == 0) {               // fused histogram: 4 edges/thread, replicated
        int e0 = (blockIdx.x * 256 + t) * 4;
        if (e0 + 4 <= E) {
            int4 d4 = *(const int4*)(ei + E + e0);
            atomicAdd(&hist_cnt[0 * NN + d4.x], 1);
            atomicAdd(&hist_cnt[1 * NN + d4.y], 1);
            atomicAdd(&hist_cnt[2 * NN + d4.z], 1);
            atomicAdd(&hist_cnt[3 * NN + d4.w], 1);
        } else {
            for (int i = 0; i < 4; ++i) {
                int e = e0 + i;
                if (e < E) atomicAdd(&hist_cnt[(e & 3) * NN + ei[E + e]], 1);
            }
        }
    }

    // ---- MODE 1: fused gather — accumulate bf16 neighbor slices into pa ----
    if (MODE == 1) {
        int p0v = 0, p1v = 0;
        if (aok) { p0v = g_rowptr[arow]; p1v = g_rowptr[arow + 1]; }
        int p = p0v;
        for (; p + 4 <= p1v; p += 4) {
            int s0 = g_srcs[p], s1 = g_srcs[p + 1];
            int s2 = g_srcs[p + 2], s3 = g_srcs[p + 3];
            bf16x8 n0[NS], n1[NS], n2[NS], n3[NS];
#pragma unroll
            for (int s = 0; s < NS; ++s) {
                n0[s] = *(const bf16x8*)(g_h0b + (size_t)s0 * HD + s * 32 + lh * 8);
                n1[s] = *(const bf16x8*)(g_h0b + (size_t)s1 * HD + s * 32 + lh * 8);
                n2[s] = *(const bf16x8*)(g_h0b + (size_t)s2 * HD + s * 32 + lh * 8);
                n3[s] = *(const bf16x8*)(g_h0b + (size_t)s3 * HD + s * 32 + lh * 8);
            }
#pragma unroll
            for (int s = 0; s < NS; ++s) {
                pa[2*s].x   += bf2f((unsigned short)n0[s][0]) + bf2f((unsigned short)n1[s][0])
                             + bf2f((unsigned short)n2[s][0]) + bf2f((unsigned short)n3[s][0]);
                pa[2*s].y   += bf2f((unsigned short)n0[s][1]) + bf2f((unsigned short)n1[s][1])
                             + bf2f((unsigned short)n2[s][1]) + bf2f((unsigned short)n3[s][1]);
                pa[2*s].z   += bf2f((unsigned short)n0[s][2]) + bf2f((unsigned short)n1[s][2])
                             + bf2f((unsigned short)n2[s][2]) + bf2f((unsigned short)n3[s][2]);
                pa[2*s].w   += bf2f((unsigned short)n0[s][3]) + bf2f((unsigned short)n1[s][3])
                             + bf2f((unsigned short)n2[s][3]) + bf2f((unsigned short)n3[s][3]);
                pa[2*s+1].x += bf2f((unsigned short)n0[s][4]) + bf2f((unsigned short)n1[s][4])
                             + bf2f((unsigned short)n2[s][4]) + bf2f((unsigned short)n3[s][4]);
                pa[2*s+1].y += bf2f((unsigned short)n0[s][5]) + bf2f((unsigned short)n1[s][5])
                             + bf2f((unsigned short)n2[s][5]) + bf2f((unsigned short)n3[s][5]);
                pa[2*s+1].z += bf2f((unsigned short)n0[s][6]) + bf2f((unsigned short)n1[s][6])
                             + bf2f((unsigned short)n2[s][6]) + bf2f((unsigned short)n3[s][6]);
                pa[2*s+1].w += bf2f((unsigned short)n0[s][7]) + bf2f((unsigned short)n1[s][7])
                             + bf2f((unsigned short)n2[s][7]) + bf2f((unsigned short)n3[s][7]);
            }
        }
        for (; p < p1v; ++p) {
            int s0 = g_srcs[p];
#pragma unroll
            for (int s = 0; s < NS; ++s) {
                bf16x8 v = *(const bf16x8*)(g_h0b + (size_t)s0 * HD + s * 32 + lh * 8);
                pa[2*s].x   += bf2f((unsigned short)v[0]);
                pa[2*s].y   += bf2f((unsigned short)v[1]);
                pa[2*s].z   += bf2f((unsigned short)v[2]);
                pa[2*s].w   += bf2f((unsigned short)v[3]);
                pa[2*s+1].x += bf2f((unsigned short)v[4]);
                pa[2*s+1].y += bf2f((unsigned short)v[5]);
                pa[2*s+1].z += bf2f((unsigned short)v[6]);
                pa[2*s+1].w += bf2f((unsigned short)v[7]);
            }
        }
    }

    // ---- convert A early ----
    bf16x8 af[NS];
#pragma unroll
    for (int s = 0; s < NS; ++s) {
        float4 q0 = pa[2 * s], q1 = pa[2 * s + 1];
        if (MODE == 2) {
            float4 sc0 = scv[2 * s], sh0 = shv[2 * s];
            float4 sc1 = scv[2 * s + 1], sh1 = shv[2 * s + 1];
            q0.x = fmaxf(q0.x * sc0.x + sh0.x, 0.f);
            q0.y = fmaxf(q0.y * sc0.y + sh0.y, 0.f);
            q0.z = fmaxf(q0.z * sc0.z + sh0.z, 0.f);
            q0.w = fmaxf(q0.w * sc0.w + sh0.w, 0.f);
            q1.x = fmaxf(q1.x * sc1.x + sh1.x, 0.f);
            q1.y = fmaxf(q1.y * sc1.y + sh1.y, 0.f);
            q1.z = fmaxf(q1.z * sc1.z + sh1.z, 0.f);
            q1.w = fmaxf(q1.w * sc1.w + sh1.w, 0.f);
        }
        af[s] = cvt8(q0, q1);
    }

    // ---- convert + stage W -> bf16 LDS ----
#pragma unroll
    for (int i = 0; i < WITER; ++i) {
        int c = t + i * 256;
        int row = c / KD4, kq = c - row * KD4;
        short4 s4v;
        s4v.x = bfr(wv[i].x); s4v.y = bfr(wv[i].y);
        s4v.z = bfr(wv[i].z); s4v.w = bfr(wv[i].w);
        *(short4*)(Wl + row * P + kq * 4) = s4v;
    }
    __syncthreads();

    f32x4 acc[6];
#pragma unroll
    for (int n = 0; n < 6; ++n) acc[n] = (f32x4){0.f, 0.f, 0.f, 0.f};

#pragma unroll
    for (int s = 0; s < NS; ++s) {
        const short* wp = Wl + s * 32 + lh * 8;
#pragma unroll
        for (int n = 0; n < 6; ++n) {
            bf16x8 bf = *(const bf16x8*)(wp + (n * 16 + l15) * P);
            acc[n] = __builtin_amdgcn_mfma_f32_16x16x32_bf16(af[s], bf, acc[n], 0, 0, 0);
        }
    }

    // ---- epilogue: bias (regs) ----
    float cv[6][4];
#pragma unroll
    for (int n = 0; n < 6; ++n) {
        float b = bias[n * 16 + l15];
#pragma unroll
        for (int r = 0; r < 4; ++r) cv[n][r] = acc[n][r] + b;
    }
    int crow[4]; bool cok[4];
#pragma unroll
    for (int r = 0; r < 4; ++r) {
        crow[r] = base + w * 16 + lh * 4 + r;
        cok[r]  = crow[r] < NN;
    }

    if (MODE == 0) {
        // C store via LDS bounce + coalesced bf16 sidecar for the fused gather
        __syncthreads();                   // all Wl (MFMA B) reads done
        float* Cl = (float*)Wl;            // [64][100]
#pragma unroll
        for (int n = 0; n < 6; ++n)
#pragma unroll
            for (int r = 0; r < 4; ++r)
                Cl[(w * 16 + lh * 4 + r) * 100 + n * 16 + l15] = cv[n][r];
        __syncthreads();
        int lrow = t >> 2;                 // 0..63
        int q4   = t & 3;
        int grow = base + lrow;
        if (grow < NN) {
            float* o = out + (size_t)grow * HD;
            unsigned short* ob = out_bf + (size_t)grow * HD;
            const float* cr = Cl + lrow * 100;
#pragma unroll
            for (int k = 0; k < 6; ++k) {
                int c4 = q4 + k * 4;       // 0..23
                float4 v = *(const float4*)(cr + c4 * 4);
                *(float4*)(o + c4 * 4) = v;
                ushort4 sv;
                sv.x = (unsigned short)bfr(v.x);
                sv.y = (unsigned short)bfr(v.y);
                sv.z = (unsigned short)bfr(v.z);
                sv.w = (unsigned short)bfr(v.w);
                *(ushort4*)(ob + c4 * 4) = sv;
            }
        }
    } else {
        // direct scalar stores (round-16 A/B: bounce costs ~2-3us with no gain)
#pragma unroll
        for (int r = 0; r < 4; ++r) {
            if (cok[r]) {
                float* o = out + (size_t)crow[r] * HD + l15;
#pragma unroll
                for (int n = 0; n < 6; ++n) o[n * 16] = cv[n][r];
            }
        }
    }

    if (MODE == 1) {
        float s[6], q[6];
#pragma unroll
        for (int n = 0; n < 6; ++n) {
            s[n] = 0.f; q[n] = 0.f;
#pragma unroll
            for (int r = 0; r < 4; ++r) {
                float v = cok[r] ? cv[n][r] : 0.f;
                s[n] += v; q[n] += v * v;
            }
        }
#pragma unroll
        for (int n = 0; n < 6; ++n) {
            s[n] += __shfl_xor(s[n], 16); s[n] += __shfl_xor(s[n], 32);
            q[n] += __shfl_xor(q[n], 16); q[n] += __shfl_xor(q[n], 32);
        }
        __syncthreads();                       // Wl dead everywhere; overlay
        float* red0 = (float*)Wl;              // [4][96]
        float* red1 = red0 + 384;              // [4][96]
        if (lh == 0) {
#pragma unroll
            for (int n = 0; n < 6; ++n) {
                red0[w * 96 + n * 16 + l15] = s[n];
                red1[w * 96 + n * 16 + l15] = q[n];
            }
        }
        __syncthreads();
        if (t < HD) {
            float S = red0[t] + red0[96 + t] + red0[192 + t] + red0[288 + t];
            float Q = red1[t] + red1[96 + t] + red1[192 + t] + red1[288 + t];
            atomicAdd(&gsum[t], S);
            atomicAdd(&gsumsq[t], Q);
        }
    }

    if (MODE == 2) {
        float s[6];
#pragma unroll
        for (int n = 0; n < 6; ++n) {
            s[n] = 0.f;
#pragma unroll
            for (int r = 0; r < 4; ++r) s[n] += cok[r] ? cv[n][r] : 0.f;
        }
#pragma unroll
        for (int n = 0; n < 6; ++n) {
            s[n] += __shfl_xor(s[n], 16); s[n] += __shfl_xor(s[n], 32);
        }
        float rq[4];
#pragma unroll
        for (int r = 0; r < 4; ++r) {
            float v = 0.f;
#pragma unroll
            for (int n = 0; n < 6; ++n) v = fmaf(cv[n][r], cv[n][r], v);
            v += __shfl_xor(v, 1); v += __shfl_xor(v, 2);
            v += __shfl_xor(v, 4); v += __shfl_xor(v, 8);
            rq[r] = v;
        }
        __syncthreads();                       // Wl dead; overlay
        float* red0 = (float*)Wl;              // [4][96]
        if (lh == 0) {
#pragma unroll
            for (int n = 0; n < 6; ++n) red0[w * 96 + n * 16 + l15] = s[n];
        }
        __syncthreads();
        if (t < HD) {
            float S = red0[t] + red0[96 + t] + red0[192 + t] + red0[288 + t];
            atomicAdd(&gcol[t], S);
        }
        if (l15 == 0) {
#pragma unroll
            for (int r = 0; r < 4; ++r)
                if (cok[r]) growss[crow[r]] = rq[r];
        }
    }
}

// ---------------- CSR build (sum 4 hist replicas; single cursor) ------------
__global__ __launch_bounds__(256) void scan_part1(const int* __restrict__ cnt,
                                                  int* __restrict__ bsum) {
    __shared__ int sh[256];
    int i = blockIdx.x * 256 + threadIdx.x;
    int t = threadIdx.x;
    int v = 0;
    if (i < NN)
        v = cnt[i] + cnt[NN + i] + cnt[2 * NN + i] + cnt[3 * NN + i];
    sh[t] = v;
    __syncthreads();
    for (int off = 128; off > 0; off >>= 1) {
        if (t < off) sh[t] += sh[t + off];
        __syncthreads();
    }
    if (t == 0) bsum[blockIdx.x] = sh[0];
}

__global__ __launch_bounds__(256) void scan_part2(int* __restrict__ bsum) {
    __shared__ int sh[256];
    int t = threadIdx.x;
    int v = (t < SCAN_NB) ? bsum[t] : 0;
    sh[t] = v;
    __syncthreads();
    for (int off = 1; off < 256; off <<= 1) {
        int u = sh[t];
        if (t >= off) u += sh[t - off];
        __syncthreads();
        sh[t] = u;
        __syncthreads();
    }
    if (t < SCAN_NB) bsum[t] = sh[t] - v;    // exclusive block offsets
}

__global__ __launch_bounds__(256) void scan_part3(int* __restrict__ cnt,
                                                  const int* __restrict__ bsum,
                                                  int* __restrict__ rowptr) {
    __shared__ int sh[256];
    int i = blockIdx.x * 256 + threadIdx.x;
    int t = threadIdx.x;
    int v = 0;
    if (i < NN)
        v = cnt[i] + cnt[NN + i] + cnt[2 * NN + i] + cnt[3 * NN + i];
    sh[t] = v;
    __syncthreads();
    for (int off = 1; off < 256; off <<= 1) {
        int u = sh[t];
        if (t >= off) u += sh[t - off];
        __syncthreads();
        sh[t] = u;
        __syncthreads();
    }
    int excl = sh[t] - v + bsum[blockIdx.x];
    if (i < NN) { rowptr[i] = excl; cnt[i] = excl; }   // cnt[0..NN): fill cursor
    if (i == NN - 1) rowptr[NN] = excl + v;
}

// fill with dst-range multipass, single cursor (round-15 A/B: replicated
// cursors cost 10%). Multipass dst-clustering kept (round-1 A/B).
__global__ __launch_bounds__(256) void fill_kernel(const int* __restrict__ ei,
                                                   int* __restrict__ cursor,
                                                   int* __restrict__ srcs, int E) {
    int t2 = blockIdx.x * 256 + threadIdx.x;
    int e0 = t2 * 2;
    int src[2], dst[2];
#pragma unroll
    for (int i = 0; i < 2; ++i) {
        int e = e0 + i;
        bool ok = e < E;
        dst[i] = ok ? ei[E + e] : -1;
        src[i] = ok ? ei[e] : 0;
    }
    for (int pass = 0; pass < 7; ++pass) {
#pragma unroll
        for (int i = 0; i < 2; ++i) {
            if (dst[i] >= 0 && (dst[i] >> 13) == pass) {
                int slot = atomicAdd(&cursor[dst[i]], 1);
                srcs[slot] = src[i];
            }
        }
    }
}

__global__ void bn_finalize_kernel(const float* __restrict__ sum, const float* __restrict__ sumsq,
                                   const float* __restrict__ gamma, const float* __restrict__ beta,
                                   float* __restrict__ scale, float* __restrict__ shift)
{
    int f = threadIdx.x;
    if (f < HD) {
        float mean = sum[f] * (1.0f / NN);
        float var  = fmaxf(sumsq[f] * (1.0f / NN) - mean * mean, 0.0f);
        float rstd = rsqrtf(var + BN_EPS);
        float sc = rstd * gamma[f];
        scale[f] = sc;
        shift[f] = beta[f] - mean * sc;
    }
}

// ---------------- PairNorm: streaming float4, in place ----------------
__global__ __launch_bounds__(256) void pn_kernel(float* l1, const float* __restrict__ colsum,
                                                 const float* __restrict__ rowss)
{
    int idx = blockIdx.x * 256 + threadIdx.x;   // float4 index
    if (idx >= NN * 24) return;
    int row = idx / 24;
    int q = idx - row * 24;
    float rs = rsqrtf(1e-6f + rowss[row]);
    float4 v = ld4(l1 + (size_t)idx * 4);
    float4 cm = ld4(colsum + q * 4);
    v.x = PN_SCALE * v.x * rs - cm.x * (1.0f / NN);
    v.y = PN_SCALE * v.y * rs - cm.y * (1.0f / NN);
    v.z = PN_SCALE * v.z * rs - cm.z * (1.0f / NN);
    v.w = PN_SCALE * v.w * rs - cm.w * (1.0f / NN);
    *(float4*)(l1 + (size_t)idx * 4) = v;
}

extern "C" void kernel_launch(void* const* d_in, const int* in_sizes, int n_in,
                              void* d_out, int out_size, void* d_ws, size_t ws_size,
                              hipStream_t stream) {
    const float* x     = (const float*)d_in[0];
    const int*   ei    = (const int*)d_in[1];
    const float* W0    = (const float*)d_in[2];
    const float* b0    = (const float*)d_in[3];
    const float* W1    = (const float*)d_in[4];
    const float* b1    = (const float*)d_in[5];
    const float* gamma = (const float*)d_in[6];
    const float* beta  = (const float*)d_in[7];
    const float* W2    = (const float*)d_in[8];
    const float* b2    = (const float*)d_in[9];

    float* out_l1 = (float*)d_out;                 // [N,96]: h -> l1 (in place)
    float* out_h0 = out_l1 + (size_t)NN * HD;      // [N,96]: h0 output

    float* stats   = (float*)d_ws;
    float* s_sum   = stats;            // 96
    float* s_sumsq = stats + HD;       // 96
    float* s_col   = stats + 2 * HD;   // 96
    float* s_scale = stats + 288;      // 96
    float* s_shift = stats + 384;      // 96
    float* rowss = stats + 1024;
    int* cnt    = (int*)(rowss + NN);              // [NREP][NN] hist; [0..NN) cursor
    int* rowptr = cnt + NREP * NN;
    int* bsum   = rowptr + NN + 2;
    int* srcs   = bsum + 256;
    unsigned short* h0b =
        (unsigned short*)(((uintptr_t)(srcs + 800000) + 15) & ~(uintptr_t)15);

    const int E = in_sizes[1] / 2;                 // 800000
    const int GB = (NN + 63) / 64;                 // 782

    zero_kernel<<<(1024 + NREP * NN + 255) / 256, 256, 0, stream>>>(stats, cnt);
    // 1) h0 = x @ W0^T + b0 (MFMA) + bf16 sidecar + replicated edge histogram
    gemm_mfma<IN_DIM, 0><<<GB, 256, 0, stream>>>(x, W0, b0, out_h0, h0b,
                                                 nullptr, nullptr,
                                                 nullptr, nullptr, nullptr, nullptr,
                                                 ei, cnt, E,
                                                 nullptr, nullptr, nullptr);
    // 2) CSR build: replica-summing scan -> multipass fill w/ single cursor
    scan_part1<<<SCAN_NB, 256, 0, stream>>>(cnt, bsum);
    scan_part2<<<1, 256, 0, stream>>>(bsum);
    scan_part3<<<SCAN_NB, 256, 0, stream>>>(cnt, bsum, rowptr);
    fill_kernel<<<(E / 2 + 255) / 256, 256, 0, stream>>>(ei, cnt, srcs, E);
    // 3+4) h = (h0 + segment_sum(h0b[src])) @ W1^T + b1  -- gather fused into
    //      gemm1's A-prep; z never materialized. Out-of-place h0 -> out_l1.
    gemm_mfma<HD, 1><<<GB, 256, 0, stream>>>(out_h0, W1, b1, out_l1, nullptr,
                                             nullptr, nullptr,
                                             s_sum, s_sumsq, nullptr, nullptr,
                                             nullptr, nullptr, 0,
                                             h0b, rowptr, srcs);
    bn_finalize_kernel<<<1, 128, 0, stream>>>(s_sum, s_sumsq, gamma, beta, s_scale, s_shift);
    // 5) l1 = relu(bn(h)) @ W2^T + b2 (in place, MFMA) + fused PN stats
    gemm_mfma<HD, 2><<<GB, 256, 0, stream>>>(out_l1, W2, b2, out_l1, nullptr,
                                             s_scale, s_shift,
                                             nullptr, nullptr, s_col, rowss,
                                             nullptr, nullptr, 0,
                                             nullptr, nullptr, nullptr);
    // 6) PairNorm finalize (streaming, in place)
    pn_kernel<<<(NN * 24 + 255) / 256, 256, 0, stream>>>(out_l1, s_col, rowss);
}